// Round 6
// baseline (586.068 us; speedup 1.0000x reference)
//
#include <hip/hip_runtime.h>
#include <cstdint>
#include <cstddef>

// Problem constants
#define L_   256
#define Q_   21
#define M_   8192
#define QQ   441
#define JCH  16            // j-blocks staged per barrier in k_main
#define SCALE    32.0f     // J scaled by 32 before fp16 quantization
#define INVSCALE 0.03125f
#define NPAIR ((L_ * (L_ - 1)) / 2)   // 32640 valid (i,j) pairs

// Jt block layout (per (i,j), TRI-PACKED): pair index = i(i-1)/2 + j.
// 21 rows (k = symbol), each row 48 B = 21 fp16(J*32) + 3 pad halves.
// Row stride 12 dwords; block padded to 1024 B (256 dwords).
// Jt = NPAIR KiB ~= 32 MiB + guard (i=255 rem-stage overread of 16 blocks).
//
// ws layout:
//   [0      .. 32640)   acc2[8160]  : per-prep-block J2 partials (f32, plain)
//   [65536  .. 65544)   scal[2]     : wsum, h2_sum (plain, prep)
//   [65544  .. 65548)   lls_total   : f32 atomic accumulator (memset to 0)
//   [65548  .. 65552)   ticket      : u32 completion counter (memset to 0)
//   [131072 .. +2MiB)   seqsP: dword[jq*M + b] = symbols j=4jq..4jq+3 (bytes)
//   [131072+2MiB ..)    Jt (fp16 blocks, tri-packed, + guard)

#define NPREPT 8160        // transpose blocks (32 x 255), 8 pairs each
#define GPREP  (NPREPT + 256 + 2)   // + seqs-pack blocks + wsum + h2

typedef _Float16 h2 __attribute__((ext_vector_type(2)));
typedef unsigned u32x4 __attribute__((ext_vector_type(4)));   // nontemporal-ok

__device__ __forceinline__ float block_reduce_sum(float v) {
    __shared__ float s[256];
    int t = threadIdx.x;
    __syncthreads();           // guard against reuse hazard
    s[t] = v;
    __syncthreads();
#pragma unroll
    for (int o = 128; o > 0; o >>= 1) {
        if (t < o) s[t] += s[t + o];
        __syncthreads();
    }
    return s[0];
}

// ---- D1: fused prep, wave-private transpose (unchanged from round 5). ----
__global__ __launch_bounds__(256) void k_prep(const float* __restrict__ J,
                                              const int* __restrict__ seqs,
                                              const float* __restrict__ w,
                                              const float* __restrict__ h,
                                              unsigned* __restrict__ Jt,
                                              unsigned* __restrict__ seqsP,
                                              float* __restrict__ acc2,
                                              float* __restrict__ scal) {
    const int bid = blockIdx.x;
    const int t = threadIdx.x;

    if (bid < NPREPT) {
        __shared__ __align__(16) float sB[4 * 2 * 448];   // 14336 B
        const int i  = (bid >> 5) + 1;                // 1..255
        const int j0 = (bid & 31) << 3;               // 8-pair chunk
        if (j0 >= i) {                                // uniform across block
            if (t == 0) acc2[bid] = 0.f;              // slot must be defined
            return;
        }
        const int jn = min(8, i - j0);
        const int wv = t >> 6;                        // wave 0..3
        const int l  = t & 63;
        const int p0 = wv << 1;                       // pair offset 0/2/4/6
        const int pn = min(2, jn - p0);               // may be <= 0
        float* sW = sB + wv * (2 * 448);              // wave-private region

        // phase 1: load pair(s) -> wave-private LDS, accumulate sum(J^2)
        float v2 = 0.f;
        for (int pp = 0; pp < pn; ++pp) {
            const float* src = J + (size_t)(i * L_ + j0 + p0 + pp) * QQ;
            float* d = sW + pp * 448;
#pragma unroll
            for (int r = 0; r < 7; ++r) {
                const int idx = (r << 6) + l;
                if (idx < QQ) {
                    float v = __builtin_nontemporal_load(src + idx);
                    d[idx] = v;
                    v2 += v * v;
                }
            }
        }
        __syncthreads();   // belt-and-braces (wave-private data; uniform)

        // phase 2: transpose-pack; one uint4 nontemporal store per lane/pair
        const int tri = i * (i - 1) / 2;
        for (int pp = 0; pp < pn; ++pp) {
            const float* s = sW + pp * 448;
            u32x4* dst = reinterpret_cast<u32x4*>(
                Jt + (size_t)(tri + j0 + p0 + pp) * 256);
            unsigned wvv[4];
#pragma unroll
            for (int c = 0; c < 4; ++c) {
                const int dd = (l << 2) | c;          // 0..255
                const int kr = dd / 12;
                const int dw = dd - 12 * kr;
                const int a0 = dw << 1;
                unsigned outw = 0;
                if (kr < Q_) {
                    float x0 = (a0     < Q_) ? s[(a0    ) * Q_ + kr] : 0.f;
                    float x1 = (a0 + 1 < Q_) ? s[(a0 + 1) * Q_ + kr] : 0.f;
                    union { _Float16 hh[2]; unsigned u; } uu;
                    uu.hh[0] = (_Float16)(x0 * SCALE);
                    uu.hh[1] = (_Float16)(x1 * SCALE);
                    outw = uu.u;
                }
                wvv[c] = outw;
            }
            u32x4 o;
            o.x = wvv[0]; o.y = wvv[1]; o.z = wvv[2]; o.w = wvv[3];
            __builtin_nontemporal_store(o, dst + l);
        }

        float r = block_reduce_sum(v2);
        if (t == 0) acc2[bid] = r;                    // private slot, no atomic
    } else if (bid < NPREPT + 256) {
        const int u  = bid - NPREPT;
        const int b  = ((u >> 3) << 8) + t;           // b-chunk u>>3, thread b
        const int jc = u & 7;                         // jq-chunk
        const int4* row = reinterpret_cast<const int4*>(seqs + (size_t)b * L_);
#pragma unroll
        for (int u8 = 0; u8 < 8; ++u8) {
            const int jq = jc * 8 + u8;
            int4 v = row[jq];
            unsigned p = (unsigned)(v.x & 255) | ((unsigned)(v.y & 255) << 8) |
                         ((unsigned)(v.z & 255) << 16) | ((unsigned)(v.w & 255) << 24);
            seqsP[jq * M_ + b] = p;
        }
    } else if (bid == NPREPT + 256) {
        float v = 0.f;
        for (int x = t; x < M_; x += 256) v += w[x];
        float r = block_reduce_sum(v);
        if (t == 0) scal[0] = r;
    } else {
        float v2 = 0.f;
        for (int x = t; x < L_ * Q_; x += 256) { float y = h[x]; v2 += y * y; }
        float r2 = block_reduce_sum(v2);
        if (t == 0) scal[1] = r2;
    }
}

// Inner body: row k of staged block jj, 12 packed fp16 adds (24 halves incl pad).
#define BODY(jj)                                                                    \
    {                                                                               \
        const unsigned kk = (idxw[(jj) >> 2] >> (((jj) & 3) * 8)) & 255u;           \
        const uint4* rp = reinterpret_cast<const uint4*>(sJ) + ((jj) * 64 + kk * 3);\
        union { uint4 u; h2 h[4]; } ra, rb, rc;                                     \
        ra.u = rp[0]; rb.u = rp[1]; rc.u = rp[2];                                   \
        acch[0]  += ra.h[0]; acch[1]  += ra.h[1];                                   \
        acch[2]  += ra.h[2]; acch[3]  += ra.h[3];                                   \
        acch[4]  += rb.h[0]; acch[5]  += rb.h[1];                                   \
        acch[6]  += rb.h[2]; acch[7]  += rb.h[3];                                   \
        acch[8]  += rc.h[0]; acch[9]  += rc.h[1];                                   \
        acch[10] += rc.h[2]; acch[11] += rc.h[3];                                   \
    }

// ---- D2a..d: main, 4-way i-parity split (2048 blocks = exact 8/CU residency).
// class r: i = 255 - 4q - r, q=0..63 (heavy first); Sum(i) = 8256/8192/8128/8064.
// Last-finishing block (ticket == 8191) performs the finalize inline.
__global__ __launch_bounds__(256, 8) void k_main(const unsigned* __restrict__ Jt,
                                                 const float* __restrict__ h,
                                                 const unsigned* __restrict__ seqsP,
                                                 const float* __restrict__ weights,
                                                 const float* __restrict__ acc2,
                                                 const float* __restrict__ scal,
                                                 float* __restrict__ lls_total,
                                                 unsigned* __restrict__ ticket,
                                                 float* __restrict__ out,
                                                 const int r4) {
    __shared__ unsigned sJ[JCH * 256];   // 16 KiB: JCH blocks x 256 dwords

    const int bid = blockIdx.x;
    const int i = 255 - ((bid >> 5) << 2) - r4;       // heavy blocks first
    const int b = ((bid & 31) << 8) + threadIdx.x;    // [0, 8192)

    // packed fp16 accumulators (scaled by SCALE); elems 21..23 stay ~0 (pads)
    h2 acch[12];
    const float* hp = h + i * Q_;
#pragma unroll
    for (int m = 0; m < 10; ++m) {
        acch[m].x = (_Float16)(hp[2 * m] * SCALE);
        acch[m].y = (_Float16)(hp[2 * m + 1] * SCALE);
    }
    acch[10].x = (_Float16)(hp[20] * SCALE); acch[10].y = (_Float16)0.f;
    acch[11].x = (_Float16)0.f;              acch[11].y = (_Float16)0.f;

    const unsigned* Jrow = Jt + (size_t)(i * (i - 1) / 2) * 256;  // tri-packed
    const int nStages = i >> 4;   // full 16-j stages
    const int rem     = i & 15;

    for (int s = 0; s < nStages; ++s) {
        const int j0 = s << 4;
        {
            const uint4* src = reinterpret_cast<const uint4*>(Jrow + j0 * 256);
            uint4* dst = reinterpret_cast<uint4*>(sJ);
#pragma unroll
            for (int n = 0; n < 4; ++n) {
                dst[n * 256 + threadIdx.x] = src[n * 256 + threadIdx.x];
            }
        }
        __syncthreads();

        unsigned idxw[JCH / 4];
#pragma unroll
        for (int q = 0; q < JCH / 4; ++q) {
            idxw[q] = seqsP[((j0 >> 2) + q) * M_ + b];
        }

#pragma unroll
        for (int jj = 0; jj < JCH; ++jj) BODY(jj);

        __syncthreads();
    }

    if (rem) {
        const int j0 = nStages << 4;   // stages 16 blocks; tail may hit guard
        {
            const uint4* src = reinterpret_cast<const uint4*>(Jrow + j0 * 256);
            uint4* dst = reinterpret_cast<uint4*>(sJ);
#pragma unroll
            for (int n = 0; n < 4; ++n) {
                dst[n * 256 + threadIdx.x] = src[n * 256 + threadIdx.x];
            }
        }
        __syncthreads();

        unsigned idxw[JCH / 4];
#pragma unroll
        for (int q = 0; q < JCH / 4; ++q) {
            idxw[q] = seqsP[((j0 >> 2) + q) * M_ + b];
        }

#pragma unroll
        for (int jj = 0; jj < JCH; ++jj) {
            if (jj >= rem) break;
            BODY(jj);
        }
    }

    // unpack logits to fp32
    float l[21];
#pragma unroll
    for (int m = 0; m < 10; ++m) {
        l[2 * m]     = (float)acch[m].x * INVSCALE;
        l[2 * m + 1] = (float)acch[m].y * INVSCALE;
    }
    l[20] = (float)acch[10].x * INVSCALE;

    // label gather from packed seqs
    unsigned lw = seqsP[(i >> 2) * M_ + b];
    int lbl = (int)((lw >> ((i & 3) * 8)) & 255u);

    float m = l[0];
#pragma unroll
    for (int a = 1; a < 21; ++a) m = fmaxf(m, l[a]);
    float s = 0.f;
    float lv = l[0];
#pragma unroll
    for (int a = 0; a < 21; ++a) {
        s += __expf(l[a] - m);
        if (a > 0) lv = (a == lbl) ? l[a] : lv;
    }
    float ll = (lv - m) - __logf(s);
    float contrib = weights[b] * ll;

    float r = block_reduce_sum(contrib);

    // completion ticket: last of 8192 blocks (across the 4 dispatches)
    // finalizes. lls_total is a single-address device-scope atomic.
    __shared__ int win;
    if (threadIdx.x == 0) {
        atomicAdd(lls_total, r);
        __threadfence();                      // order lls add before ticket
        unsigned old = atomicAdd(ticket, 1u);
        win = (old == 8191u) ? 1 : 0;
    }
    __syncthreads();
    if (win) {
        __threadfence();                      // acquire
        const int t = threadIdx.x;
        float j2p = 0.f;
        for (int x = t; x < NPREPT; x += 256) j2p += acc2[x];  // prep-boundary-safe
        float j2 = block_reduce_sum(j2p);
        if (t == 0) {
            float lls = atomicAdd(lls_total, 0.0f);   // coherent read
            float wsum = fmaxf(scal[0], 1e-12f);
            float nll = -lls / wsum;
            float reg = 0.5e-6f * scal[1] + 0.5e-4f * j2;
            out[0] = nll + reg;
            out[1] = nll;
            out[2] = reg;
        }
    }
}

extern "C" void kernel_launch(void* const* d_in, const int* in_sizes, int n_in,
                              void* d_out, int out_size, void* d_ws, size_t ws_size,
                              hipStream_t stream) {
    const int*   seqs    = (const int*)d_in[0];
    const float* weights = (const float*)d_in[1];
    const float* h       = (const float*)d_in[2];
    const float* J       = (const float*)d_in[3];
    float* out = (float*)d_out;

    char* ws = (char*)d_ws;
    float*    acc2   = (float*)ws;                        // 8160 slots
    float*    scal   = (float*)(ws + 65536);              // wsum, h2
    float*    llst   = (float*)(ws + 65544);              // lls atomic
    unsigned* ticket = (unsigned*)(ws + 65548);           // completion counter
    unsigned* seqsP  = (unsigned*)(ws + 131072);          // 2 MiB
    unsigned* Jt     = (unsigned*)(ws + 131072 + (size_t)(L_ / 4) * M_ * sizeof(unsigned));

    hipMemsetAsync(ws + 65544, 0, 8, stream);             // lls_total + ticket

    k_prep<<<GPREP, 256, 0, stream>>>(J, seqs, weights, h, Jt, seqsP, acc2, scal);
    for (int r = 0; r < 4; ++r) {
        k_main<<<2048, 256, 0, stream>>>(Jt, h, seqsP, weights, acc2, scal,
                                         llst, ticket, out, r);
    }
}

// Round 7
// 372.677 us; speedup vs baseline: 1.5726x; 1.5726x over previous
//
#include <hip/hip_runtime.h>
#include <cstdint>
#include <cstddef>

// Problem constants
#define L_   256
#define Q_   21
#define M_   8192
#define QQ   441
#define JCH  16            // j-blocks staged per barrier in k_main
#define SCALE    32.0f     // J scaled by 32 before fp16 quantization
#define INVSCALE 0.03125f
#define NPAIR ((L_ * (L_ - 1)) / 2)   // 32640 valid (i,j) pairs

// Jt block layout (per (i,j), TRI-PACKED): pair index = i(i-1)/2 + j.
// 21 rows (k = symbol), each row 48 B = 21 fp16(J*32) + 3 pad halves.
// Row stride 12 dwords; block padded to 1024 B (256 dwords).
// Jt = NPAIR KiB ~= 32 MiB + guard (i=255 rem-stage overread).
//
// ws layout (no memset needed -- every slot is plain-stored exactly once):
//   [0      .. 16384)   acc2[4080]  : per-prep-block J2 partials (f32)
//   [16384  .. 49152)   accL[8192]  : per-main-block ll partials (f32)
//   [49152  .. 49160)   scal[2]     : wsum, h2_sum
//   [65536  .. +2MiB)   seqsP: dword[jq*M + b] = symbols j=4jq..4jq+3 (bytes)
//   [65536+2MiB ..)     Jt (fp16 blocks, tri-packed, + guard)

#define NPREPT 4080        // transpose blocks (16 x 255)
#define GPREP  (NPREPT + 256 + 2)   // + seqs-pack blocks + wsum + h2

typedef _Float16 h2 __attribute__((ext_vector_type(2)));
typedef float    f32x4 __attribute__((ext_vector_type(4)));   // nontemporal-ok
typedef unsigned u32x4 __attribute__((ext_vector_type(4)));   // nontemporal-ok

typedef const __attribute__((address_space(1))) unsigned  glob_u32;
typedef __attribute__((address_space(3))) unsigned        lds_u32;

__device__ __forceinline__ float block_reduce_sum(float v) {
    __shared__ float s[256];
    int t = threadIdx.x;
    __syncthreads();           // guard against reuse hazard
    s[t] = v;
    __syncthreads();
#pragma unroll
    for (int o = 128; o > 0; o >>= 1) {
        if (t < o) s[t] += s[t + o];
        __syncthreads();
    }
    return s[0];
}

// ---- D1: fused prep (identical to the round-4 version that measured best).
// blocks [0,4080): J transpose; [4080,4336): seqs pack; 4336: wsum; 4337: h^2.
__global__ __launch_bounds__(256) void k_prep(const float* __restrict__ J,
                                              const int* __restrict__ seqs,
                                              const float* __restrict__ w,
                                              const float* __restrict__ h,
                                              unsigned* __restrict__ Jt,
                                              unsigned* __restrict__ seqsP,
                                              float* __restrict__ acc2,
                                              float* __restrict__ scal) {
    const int bid = blockIdx.x;
    const int t = threadIdx.x;

    if (bid < NPREPT) {
        __shared__ __align__(16) float sB[16 * QQ];   // 28224 B
        const int i  = (bid >> 4) + 1;                // 1..255
        const int j0 = (bid & 15) << 4;
        if (j0 >= i) {                                 // uniform across block
            if (t == 0) acc2[bid] = 0.f;               // slot must be defined
            return;
        }
        const int jn = min(16, i - j0);

        const float* src = J + (size_t)(i * L_ + j0) * QQ;   // 16B-aligned
        const int ndw = jn * QQ;
        const int nf4 = ndw >> 2;
        const int rem = ndw & 3;

        // phase 1: contiguous nontemporal float4 load -> LDS, sum(J^2)
        float v2 = 0.f;
        {
            const f32x4* src4 = reinterpret_cast<const f32x4*>(src);
            f32x4* s4 = reinterpret_cast<f32x4*>(sB);
            for (int q = t; q < nf4; q += 256) {
                f32x4 v = __builtin_nontemporal_load(src4 + q);
                s4[q] = v;
                v2 += v.x * v.x + v.y * v.y + v.z * v.z + v.w * v.w;
            }
            if (t < rem) {
                float v = src[(nf4 << 2) + t];
                sB[(nf4 << 2) + t] = v;
                v2 += v * v;
            }
        }
        __syncthreads();

        // phase 2: transpose-pack, coalesced nontemporal uint4 stores
        {
            const int tri = i * (i - 1) / 2;
            const int nu4 = jn << 6;
            u32x4* dst = reinterpret_cast<u32x4*>(Jt + (size_t)(tri + j0) * 256);
            for (int g = t; g < nu4; g += 256) {
                const float* s = sB + (g >> 6) * QQ;
                unsigned wv[4];
#pragma unroll
                for (int c = 0; c < 4; ++c) {
                    const int dd = ((g & 63) << 2) | c;   // 0..255
                    const int kr = dd / 12;
                    const int dw = dd - 12 * kr;
                    const int a0 = dw << 1;
                    unsigned outw = 0;
                    if (kr < Q_) {
                        float x0 = (a0     < Q_) ? s[(a0    ) * Q_ + kr] : 0.f;
                        float x1 = (a0 + 1 < Q_) ? s[(a0 + 1) * Q_ + kr] : 0.f;
                        union { _Float16 hh[2]; unsigned u; } uu;
                        uu.hh[0] = (_Float16)(x0 * SCALE);
                        uu.hh[1] = (_Float16)(x1 * SCALE);
                        outw = uu.u;
                    }
                    wv[c] = outw;
                }
                u32x4 o;
                o.x = wv[0]; o.y = wv[1]; o.z = wv[2]; o.w = wv[3];
                __builtin_nontemporal_store(o, dst + g);
            }
        }

        float r = block_reduce_sum(v2);
        if (t == 0) acc2[bid] = r;                    // private slot, no atomic
    } else if (bid < NPREPT + 256) {
        const int u  = bid - NPREPT;
        const int b  = ((u >> 3) << 8) + t;           // b-chunk u>>3, thread b
        const int jc = u & 7;                         // jq-chunk
        const int4* row = reinterpret_cast<const int4*>(seqs + (size_t)b * L_);
#pragma unroll
        for (int u8 = 0; u8 < 8; ++u8) {
            const int jq = jc * 8 + u8;
            int4 v = row[jq];
            unsigned p = (unsigned)(v.x & 255) | ((unsigned)(v.y & 255) << 8) |
                         ((unsigned)(v.z & 255) << 16) | ((unsigned)(v.w & 255) << 24);
            seqsP[jq * M_ + b] = p;
        }
    } else if (bid == NPREPT + 256) {
        float v = 0.f;
        for (int x = t; x < M_; x += 256) v += w[x];
        float r = block_reduce_sum(v);
        if (t == 0) scal[0] = r;
    } else {
        float v2 = 0.f;
        for (int x = t; x < L_ * Q_; x += 256) { float y = h[x]; v2 += y * y; }
        float r2 = block_reduce_sum(v2);
        if (t == 0) scal[1] = r2;
    }
}

// Inner body: row k of staged block jj, 12 packed fp16 adds (24 halves incl pad).
#define BODY(jj)                                                                    \
    {                                                                               \
        const unsigned kk = (idxw[(jj) >> 2] >> (((jj) & 3) * 8)) & 255u;           \
        const uint4* rp = reinterpret_cast<const uint4*>(sJ) + ((jj) * 64 + kk * 3);\
        union { uint4 u; h2 h[4]; } ra, rb, rc;                                     \
        ra.u = rp[0]; rb.u = rp[1]; rc.u = rp[2];                                   \
        acch[0]  += ra.h[0]; acch[1]  += ra.h[1];                                   \
        acch[2]  += ra.h[2]; acch[3]  += ra.h[3];                                   \
        acch[4]  += rb.h[0]; acch[5]  += rb.h[1];                                   \
        acch[6]  += rb.h[2]; acch[7]  += rb.h[3];                                   \
        acch[8]  += rc.h[0]; acch[9]  += rc.h[1];                                   \
        acch[10] += rc.h[2]; acch[11] += rc.h[3];                                   \
    }

// Staging via async global->LDS (linear mode: wave-uniform base + lane*16).
// Removes 4 ds_write_b128 + the VGPR round-trip per thread per stage.
#define STAGE(j0)                                                                   \
    {                                                                               \
        const unsigned* gsrc = Jrow + (j0) * 256;                                   \
        _Pragma("unroll")                                                           \
        for (int n = 0; n < 4; ++n) {                                               \
            const int idx = (n * 256 + threadIdx.x) * 4;   /* dword index */        \
            __builtin_amdgcn_global_load_lds(                                       \
                (glob_u32*)(gsrc + idx), (lds_u32*)(&sJ[idx]), 16, 0, 0);           \
        }                                                                           \
    }

// ---- D2: main (round-4 structure; staging switched to global_load_lds). ----
__global__ __launch_bounds__(256, 8) void k_main(const unsigned* __restrict__ Jt,
                                                 const float* __restrict__ h,
                                                 const unsigned* __restrict__ seqsP,
                                                 const float* __restrict__ weights,
                                                 float* __restrict__ accL) {
    __shared__ unsigned sJ[JCH * 256];   // 16 KiB: JCH blocks x 256 dwords

    const int bid = blockIdx.x;
    const int i = (L_ - 1) - (bid >> 5);              // heavy blocks first
    const int b = ((bid & 31) << 8) + threadIdx.x;    // [0, 8192)

    // packed fp16 accumulators (scaled by SCALE); elems 21..23 stay ~0 (pads)
    h2 acch[12];
    const float* hp = h + i * Q_;
#pragma unroll
    for (int m = 0; m < 10; ++m) {
        acch[m].x = (_Float16)(hp[2 * m] * SCALE);
        acch[m].y = (_Float16)(hp[2 * m + 1] * SCALE);
    }
    acch[10].x = (_Float16)(hp[20] * SCALE); acch[10].y = (_Float16)0.f;
    acch[11].x = (_Float16)0.f;              acch[11].y = (_Float16)0.f;

    const unsigned* Jrow = Jt + (size_t)(i * (i - 1) / 2) * 256;  // tri-packed
    const int nStages = i >> 4;   // full 16-j stages
    const int rem     = i & 15;

    for (int s = 0; s < nStages; ++s) {
        const int j0 = s << 4;
        STAGE(j0);
        __syncthreads();          // compiler drains vmcnt before barrier

        unsigned idxw[JCH / 4];
#pragma unroll
        for (int q = 0; q < JCH / 4; ++q) {
            idxw[q] = seqsP[((j0 >> 2) + q) * M_ + b];
        }

#pragma unroll
        for (int jj = 0; jj < JCH; ++jj) BODY(jj);

        __syncthreads();
    }

    if (rem) {
        const int j0 = nStages << 4;   // stages 16 blocks; tail may hit guard
        STAGE(j0);
        __syncthreads();

        unsigned idxw[JCH / 4];
#pragma unroll
        for (int q = 0; q < JCH / 4; ++q) {
            idxw[q] = seqsP[((j0 >> 2) + q) * M_ + b];
        }

#pragma unroll
        for (int jj = 0; jj < JCH; ++jj) {
            if (jj >= rem) break;
            BODY(jj);
        }
    }

    // unpack logits to fp32
    float l[21];
#pragma unroll
    for (int m = 0; m < 10; ++m) {
        l[2 * m]     = (float)acch[m].x * INVSCALE;
        l[2 * m + 1] = (float)acch[m].y * INVSCALE;
    }
    l[20] = (float)acch[10].x * INVSCALE;

    // label gather from packed seqs
    unsigned lw = seqsP[(i >> 2) * M_ + b];
    int lbl = (int)((lw >> ((i & 3) * 8)) & 255u);

    float m = l[0];
#pragma unroll
    for (int a = 1; a < 21; ++a) m = fmaxf(m, l[a]);
    float s = 0.f;
    float lv = l[0];
#pragma unroll
    for (int a = 0; a < 21; ++a) {
        s += __expf(l[a] - m);
        if (a > 0) lv = (a == lbl) ? l[a] : lv;
    }
    float ll = (lv - m) - __logf(s);
    float contrib = weights[b] * ll;

    float r = block_reduce_sum(contrib);
    if (threadIdx.x == 0) accL[bid] = r;              // private slot, no atomic
}

// ---- D3: finalize -- reduce all private slots + compose outputs ----
__global__ __launch_bounds__(256) void k_final(const float* __restrict__ acc2,
                                               const float* __restrict__ accL,
                                               const float* __restrict__ scal,
                                               float* __restrict__ out) {
    int t = threadIdx.x;
    float j2 = 0.f;
    for (int x = t; x < NPREPT; x += 256) j2 += acc2[x];
    j2 = block_reduce_sum(j2);
    float lls = 0.f;
    for (int x = t; x < M_; x += 256) lls += accL[x];
    lls = block_reduce_sum(lls);
    if (t == 0) {
        float wsum = fmaxf(scal[0], 1e-12f);
        float nll = -lls / wsum;
        float reg = 0.5e-6f * scal[1] + 0.5e-4f * j2;
        out[0] = nll + reg;
        out[1] = nll;
        out[2] = reg;
    }
}

extern "C" void kernel_launch(void* const* d_in, const int* in_sizes, int n_in,
                              void* d_out, int out_size, void* d_ws, size_t ws_size,
                              hipStream_t stream) {
    const int*   seqs    = (const int*)d_in[0];
    const float* weights = (const float*)d_in[1];
    const float* h       = (const float*)d_in[2];
    const float* J       = (const float*)d_in[3];
    float* out = (float*)d_out;

    char* ws = (char*)d_ws;
    float*    acc2  = (float*)ws;                         // 4080 slots
    float*    accL  = (float*)(ws + 16384);               // 8192 slots
    float*    scal  = (float*)(ws + 49152);               // wsum, h2
    unsigned* seqsP = (unsigned*)(ws + 65536);            // 2 MiB
    unsigned* Jt    = (unsigned*)(ws + 65536 + (size_t)(L_ / 4) * M_ * sizeof(unsigned));

    // no memset: every ws slot consumed is plain-stored exactly once upstream

    k_prep<<<GPREP, 256, 0, stream>>>(J, seqs, weights, h, Jt, seqsP, acc2, scal);
    k_main<<<L_ * (M_ / 256), 256, 0, stream>>>(Jt, h, seqsP, weights, accL);
    k_final<<<1, 256, 0, stream>>>(acc2, accL, scal, out);
}